// Round 7
// baseline (299.660 us; speedup 1.0000x reference)
//
#include <hip/hip_runtime.h>
#include <hip/hip_bf16.h>

#define EPSV 1e-5f

typedef __attribute__((ext_vector_type(8))) short bf16x8;
typedef __attribute__((ext_vector_type(4))) float f32x4;

static __device__ __forceinline__ short f2bf(float f) {
  return __builtin_bit_cast(short, __float2bfloat16(f));
}

// ---------------- node pipeline: MFMA (unchanged from R6) ----------------
__global__ __launch_bounds__(256) void node_mfma_kernel(
    const float* __restrict__ node_feats, const float* __restrict__ cond,
    const float* __restrict__ W_cond, const float* __restrict__ b_cond,
    const float* __restrict__ W_film, const float* __restrict__ b_film,
    float* __restrict__ h, int N)
{
  __shared__ __align__(16) short cond_s[16][264];
  __shared__ __align__(16) short nf_s[16][136];
  __shared__ __align__(16) float gb_s[16][132];
  __shared__ __align__(16) float h_s[16][68];

  const int t = threadIdx.x;
  const int lane = t & 63;
  const int w = t >> 6;
  const int r16 = lane & 15;
  const int kb = lane >> 4;

  const int colc0 = w * 32 + r16;
  const int colc1 = w * 32 + 16 + r16;
  bf16x8 bc[2][8];
#pragma unroll
  for (int ks = 0; ks < 8; ++ks)
#pragma unroll
    for (int j = 0; j < 8; ++j) {
      const int k = ks * 32 + kb * 8 + j;
      bc[0][ks][j] = f2bf(W_cond[k * 128 + colc0]);
      bc[1][ks][j] = f2bf(W_cond[k * 128 + colc1]);
    }
  const int colf = w * 16 + r16;
  bf16x8 bfm[4];
#pragma unroll
  for (int ks = 0; ks < 4; ++ks)
#pragma unroll
    for (int j = 0; j < 8; ++j)
      bfm[ks][j] = f2bf(W_film[(ks * 32 + kb * 8 + j) * 64 + colf]);
  const float bbc0 = b_cond[colc0] + (w < 2 ? 1.0f : 0.0f);
  const float bbc1 = b_cond[colc1] + (w < 2 ? 1.0f : 0.0f);
  const float bbf = b_film[colf];

  const int ntiles = (N + 15) >> 4;
  for (int tile = blockIdx.x; tile < ntiles; tile += gridDim.x) {
    const int n0 = tile << 4;
    const int rows = min(16, N - n0);
    {
      const float4* c4 = (const float4*)(cond + (size_t)n0 * 256);
#pragma unroll
      for (int it = 0; it < 4; ++it) {
        const int i = t + it * 256;
        const int row = i >> 6, c = i & 63;
        const float4 v = (row < rows) ? c4[i] : make_float4(0.f, 0.f, 0.f, 0.f);
        short* p = &cond_s[row][c * 4];
        p[0] = f2bf(v.x); p[1] = f2bf(v.y); p[2] = f2bf(v.z); p[3] = f2bf(v.w);
      }
      const float4* n4 = (const float4*)(node_feats + (size_t)n0 * 128);
#pragma unroll
      for (int it = 0; it < 2; ++it) {
        const int i = t + it * 256;
        const int row = i >> 5, c = i & 31;
        const float4 v = (row < rows) ? n4[i] : make_float4(0.f, 0.f, 0.f, 0.f);
        short* p = &nf_s[row][c * 4];
        p[0] = f2bf(v.x); p[1] = f2bf(v.y); p[2] = f2bf(v.z); p[3] = f2bf(v.w);
      }
    }
    __syncthreads();

    f32x4 cg0 = {0.f, 0.f, 0.f, 0.f}, cg1 = {0.f, 0.f, 0.f, 0.f};
#pragma unroll
    for (int ks = 0; ks < 8; ++ks) {
      const bf16x8 a = *(const bf16x8*)&cond_s[r16][ks * 32 + kb * 8];
      cg0 = __builtin_amdgcn_mfma_f32_16x16x32_bf16(a, bc[0][ks], cg0, 0, 0, 0);
      cg1 = __builtin_amdgcn_mfma_f32_16x16x32_bf16(a, bc[1][ks], cg1, 0, 0, 0);
    }
    f32x4 ch = {0.f, 0.f, 0.f, 0.f};
#pragma unroll
    for (int ks = 0; ks < 4; ++ks) {
      const bf16x8 a = *(const bf16x8*)&nf_s[r16][ks * 32 + kb * 8];
      ch = __builtin_amdgcn_mfma_f32_16x16x32_bf16(a, bfm[ks], ch, 0, 0, 0);
    }
#pragma unroll
    for (int j = 0; j < 4; ++j) {
      gb_s[kb * 4 + j][colc0] = cg0[j] + bbc0;
      gb_s[kb * 4 + j][colc1] = cg1[j] + bbc1;
      h_s[kb * 4 + j][colf]   = ch[j] + bbf;
    }
    __syncthreads();

#pragma unroll
    for (int rr = 0; rr < 4; ++rr) {
      const int r = w * 4 + rr;
      const float v = h_s[r][lane];
      float s = v, q = v * v;
#pragma unroll
      for (int off = 1; off < 64; off <<= 1) {
        s += __shfl_xor(s, off, 64);
        q += __shfl_xor(q, off, 64);
      }
      const float mu = s * (1.0f / 64.0f);
      const float var = q * (1.0f / 64.0f) - mu * mu;
      const float hn = (v - mu) * rsqrtf(var + EPSV);
      const float gm = gb_s[r][lane];
      const float bt = gb_s[r][64 + lane];
      if (r < rows)
        h[(size_t)(n0 + r) * 64 + lane] = fmaxf(fmaf(gm, hn, bt), 0.0f);
    }
  }
}

// ---------------- edge_feats f32 -> bf16 streaming convert ----------------
__global__ __launch_bounds__(256) void ef16_kernel(
    const float* __restrict__ ef, short* __restrict__ ef16, long long nchunks)
{
  const long long stride = (long long)gridDim.x * blockDim.x;
  for (long long i = blockIdx.x * (long long)blockDim.x + threadIdx.x;
       i < nchunks; i += stride) {
    const f32x4 v0 = *(const f32x4*)(ef + i * 8);
    const f32x4 v1 = *(const f32x4*)(ef + i * 8 + 4);
    bf16x8 o;
#pragma unroll
    for (int j = 0; j < 4; ++j) { o[j] = f2bf(v0[j]); o[j + 4] = f2bf(v1[j]); }
    *(bf16x8*)(ef16 + i * 8) = o;
  }
}

// ---------------- counting sort by dst + tile list ----------------
__global__ __launch_bounds__(256) void hist_kernel(
    const int* __restrict__ dst, int* __restrict__ cnt, int E)
{
  const int stride = gridDim.x * blockDim.x;
  for (int e = blockIdx.x * blockDim.x + threadIdx.x; e < E; e += stride)
    atomicAdd(&cnt[dst[e]], 1);
}

__global__ __launch_bounds__(256) void scan_blocks(
    const int* __restrict__ cnt, int* __restrict__ binst, int* __restrict__ tileoff,
    int* __restrict__ esum, int* __restrict__ tsum, int N)
{
  __shared__ int we[4], wt[4];
  const int t = threadIdx.x, lane = t & 63, w = t >> 6;
  const int i = blockIdx.x * 256 + t;
  const int c  = (i < N) ? cnt[i] : 0;
  const int nt = (c + 15) >> 4;
  int pe = c, pt = nt;
#pragma unroll
  for (int off = 1; off < 64; off <<= 1) {
    const int ae = __shfl_up(pe, off, 64);
    const int at = __shfl_up(pt, off, 64);
    if (lane >= off) { pe += ae; pt += at; }
  }
  if (lane == 63) { we[w] = pe; wt[w] = pt; }
  __syncthreads();
  if (t == 0) {
    int re = 0, rt = 0;
#pragma unroll
    for (int k = 0; k < 4; ++k) { const int a = we[k], b = wt[k]; we[k] = re; wt[k] = rt; re += a; rt += b; }
    esum[blockIdx.x] = re;
    tsum[blockIdx.x] = rt;
  }
  __syncthreads();
  if (i < N) {
    binst[i]   = we[w] + pe - c;
    tileoff[i] = wt[w] + pt - nt;
  }
}

__global__ __launch_bounds__(256) void scan_tops(
    int* __restrict__ esum, int* __restrict__ tsum, int* __restrict__ Tcnt, int NB)
{
  __shared__ int we[4], wt[4];
  const int t = threadIdx.x, lane = t & 63, w = t >> 6;
  const int c  = (t < NB) ? esum[t] : 0;
  const int nt = (t < NB) ? tsum[t] : 0;
  int pe = c, pt = nt;
#pragma unroll
  for (int off = 1; off < 64; off <<= 1) {
    const int ae = __shfl_up(pe, off, 64);
    const int at = __shfl_up(pt, off, 64);
    if (lane >= off) { pe += ae; pt += at; }
  }
  if (lane == 63) { we[w] = pe; wt[w] = pt; }
  __syncthreads();
  if (t == 0) {
    int re = 0, rt = 0;
#pragma unroll
    for (int k = 0; k < 4; ++k) { const int a = we[k], b = wt[k]; we[k] = re; wt[k] = rt; re += a; rt += b; }
    Tcnt[0] = rt;
  }
  __syncthreads();
  if (t < NB) {
    esum[t] = we[w] + pe - c;
    tsum[t] = wt[w] + pt - nt;
  }
}

__global__ __launch_bounds__(256) void scan_apply(
    int* __restrict__ binst, int* __restrict__ tileoff, int* __restrict__ cursor,
    const int* __restrict__ esum, const int* __restrict__ tsum, int N)
{
  const int i = blockIdx.x * 256 + threadIdx.x;
  if (i < N) {
    const int b = binst[i] + esum[blockIdx.x];
    binst[i] = b;
    cursor[i] = b;
    tileoff[i] += tsum[blockIdx.x];
  }
}

__global__ __launch_bounds__(256) void emit_tiles(
    const int* __restrict__ cnt, const int* __restrict__ binst,
    const int* __restrict__ tileoff,
    int* __restrict__ tileA, int* __restrict__ tileB, int N)
{
  const int stride = gridDim.x * blockDim.x;
  for (int d = blockIdx.x * blockDim.x + threadIdx.x; d < N; d += stride) {
    const int c = cnt[d];
    const int tb = tileoff[d];
    const int st = binst[d];
    const int nt = (c + 15) >> 4;
    for (int k = 0; k < nt; ++k) {
      tileA[tb + k] = d | (min(16, c - 16 * k) << 20);
      tileB[tb + k] = st + 16 * k;
    }
  }
}

// fill: packed per-slot record {src, mirror, ew_bits, 0}
__global__ __launch_bounds__(256) void fill_kernel(
    const int* __restrict__ dst, const int* __restrict__ src,
    const int* __restrict__ mirror, const float* __restrict__ ew,
    int* __restrict__ cursor, int4* __restrict__ rec, int E)
{
  const int stride = gridDim.x * blockDim.x;
  for (int e = blockIdx.x * blockDim.x + threadIdx.x; e < E; e += stride) {
    const int pos = atomicAdd(&cursor[dst[e]], 1);
    rec[pos] = make_int4(src[e], mirror[e], __float_as_int(ew[e]), 0);
  }
}

// ---------------- fused gather-MFMA-accumulate over uniform tiles ----------------
template <bool EF16>
__global__ __launch_bounds__(256) void gather_tiles3_kernel(
    const float* __restrict__ ef32, const short* __restrict__ ef16,
    const int4* __restrict__ rec,
    const int* __restrict__ tileA, const int* __restrict__ tileB,
    const int* __restrict__ Tcnt,
    const float* __restrict__ W_edge, const float* __restrict__ b_edge,
    const float* __restrict__ h, float* __restrict__ out)
{
  const int lane = threadIdx.x & 63;
  const int r16  = lane & 15;
  const int kb   = lane >> 4;
  const int gw   = (int)((blockIdx.x * blockDim.x + threadIdx.x) >> 6);
  const int nw   = (int)((gridDim.x * blockDim.x) >> 6);
  const int T    = Tcnt[0];

  bf16x8 bfr[4][2];
#pragma unroll
  for (int nb = 0; nb < 4; ++nb)
#pragma unroll
    for (int ks = 0; ks < 2; ++ks)
#pragma unroll
      for (int j = 0; j < 8; ++j) {
        const int k = ks * 32 + kb * 8 + j;
        bfr[nb][ks][j] = f2bf(W_edge[k * 64 + nb * 16 + r16]);
      }
  float bb[4];
#pragma unroll
  for (int nb = 0; nb < 4; ++nb) bb[nb] = b_edge[nb * 16 + r16];

  int ti = gw;
  int aCur = 0, stCur = 0;
  if (ti < T) { aCur = tileA[ti]; stCur = tileB[ti]; }
  while (ti < T) {
    const int tn = ti + nw;
    int aNxt = 0, stNxt = 0;
    if (tn < T) { aNxt = tileA[tn]; stNxt = tileB[tn]; }  // prefetch next meta

    const int d  = aCur & 0xFFFFF;
    const int nv = aCur >> 20;
    const bool val = r16 < nv;
    const int4 rc = rec[stCur + (val ? r16 : 0)];
    const int sv = rc.x;
    const int mv = val ? rc.y : 0;
    const float wv = val ? __int_as_float(rc.z) : 0.0f;

    bf16x8 af0, af1;
    if (EF16) {
      const short* ar = ef16 + (size_t)mv * 64 + kb * 8;
      af0 = *(const bf16x8*)(ar);
      af1 = *(const bf16x8*)(ar + 32);
    } else {
      const float* ar = ef32 + (size_t)mv * 64 + kb * 8;
      const f32x4 a0 = *(const f32x4*)(ar);
      const f32x4 a1 = *(const f32x4*)(ar + 4);
      const f32x4 a2 = *(const f32x4*)(ar + 32);
      const f32x4 a3 = *(const f32x4*)(ar + 36);
#pragma unroll
      for (int j = 0; j < 4; ++j) {
        af0[j]     = f2bf(a0[j]);
        af0[j + 4] = f2bf(a1[j]);
        af1[j]     = f2bf(a2[j]);
        af1[j + 4] = f2bf(a3[j]);
      }
    }

    float ewj[4];
    float hv[4][4];
#pragma unroll
    for (int j = 0; j < 4; ++j) {
      const int row = kb * 4 + j;
      const int sj = __shfl(sv, row, 64);
      ewj[j] = __shfl(wv, row, 64);
      const float* hrow = h + (size_t)sj * 64 + r16;
#pragma unroll
      for (int nb = 0; nb < 4; ++nb) hv[j][nb] = hrow[nb * 16];
    }

    f32x4 c[4];
#pragma unroll
    for (int nb = 0; nb < 4; ++nb) c[nb] = (f32x4){0.f, 0.f, 0.f, 0.f};
#pragma unroll
    for (int nb = 0; nb < 4; ++nb) {
      c[nb] = __builtin_amdgcn_mfma_f32_16x16x32_bf16(af0, bfr[nb][0], c[nb], 0, 0, 0);
      c[nb] = __builtin_amdgcn_mfma_f32_16x16x32_bf16(af1, bfr[nb][1], c[nb], 0, 0, 0);
    }

    float racc[4];
#pragma unroll
    for (int nb = 0; nb < 4; ++nb) {
      const float s0 = c[nb][0] + bb[nb];
      const float s1 = c[nb][1] + bb[nb];
      const float s2 = c[nb][2] + bb[nb];
      const float s3 = c[nb][3] + bb[nb];
      float r = (1.0f - 2.0f / (__expf(2.0f * s0) + 1.0f)) * ewj[0] * hv[0][nb];
      r = fmaf((1.0f - 2.0f / (__expf(2.0f * s1) + 1.0f)) * ewj[1], hv[1][nb], r);
      r = fmaf((1.0f - 2.0f / (__expf(2.0f * s2) + 1.0f)) * ewj[2], hv[2][nb], r);
      r = fmaf((1.0f - 2.0f / (__expf(2.0f * s3) + 1.0f)) * ewj[3], hv[3][nb], r);
      r += __shfl_xor(r, 16, 64);
      r += __shfl_xor(r, 32, 64);
      racc[nb] = r;
    }
    float v = racc[0];
    if (kb == 1) v = racc[1];
    if (kb == 2) v = racc[2];
    if (kb == 3) v = racc[3];
    atomicAdd(&out[(size_t)d * 64 + lane], v);

    ti = tn; aCur = aNxt; stCur = stNxt;
  }
}

extern "C" void kernel_launch(void* const* d_in, const int* in_sizes, int n_in,
                              void* d_out, int out_size, void* d_ws, size_t ws_size,
                              hipStream_t stream) {
  const float* node_feats   = (const float*)d_in[0];
  const float* edge_feats   = (const float*)d_in[1];
  const float* cond         = (const float*)d_in[2];
  const float* edge_weights = (const float*)d_in[3];
  const int*   src          = (const int*)d_in[4];
  const int*   dst          = (const int*)d_in[5];
  const int*   mirror       = (const int*)d_in[6];
  const float* W_edge       = (const float*)d_in[7];
  const float* b_edge       = (const float*)d_in[8];
  const float* W_cond       = (const float*)d_in[9];
  const float* b_cond       = (const float*)d_in[10];
  const float* W_film       = (const float*)d_in[11];
  const float* b_film       = (const float*)d_in[12];
  const int N = in_sizes[0] / 128;
  const int E = in_sizes[4];
  const int NB = (N + 255) / 256;
  const int Tmax = N + E / 16 + 1;

  char* ws = (char*)d_ws;
  char* ws0 = ws;
  float* h      = (float*)ws;  ws += (size_t)N * 64 * sizeof(float);
  int* cnt      = (int*)ws;    ws += (size_t)N * sizeof(int);
  int* binst    = (int*)ws;    ws += (size_t)N * sizeof(int);
  int* tileoff  = (int*)ws;    ws += (size_t)N * sizeof(int);
  int* cursor   = (int*)ws;    ws += (size_t)N * sizeof(int);
  int* tileA    = (int*)ws;    ws += (size_t)Tmax * sizeof(int);
  int* tileB    = (int*)ws;    ws += (size_t)Tmax * sizeof(int);
  int* esum     = (int*)ws;    ws += 256 * sizeof(int);
  int* tsum     = (int*)ws;    ws += 256 * sizeof(int);
  int* Tcnt     = (int*)ws;    ws += 256 * sizeof(int);   // padded for alignment
  ws = ws0 + (((ws - ws0) + 15) & ~(size_t)15);
  int4* rec     = (int4*)ws;   ws += (size_t)E * sizeof(int4);
  short* ef16   = (short*)ws;  ws += (size_t)E * 64 * sizeof(short);
  const bool use16 = ((size_t)(ws - ws0) <= ws_size);

  node_mfma_kernel<<<1024, 256, 0, stream>>>(
      node_feats, cond, W_cond, b_cond, W_film, b_film, h, N);

  hipMemsetAsync(cnt, 0, (size_t)N * sizeof(int), stream);
  hipMemsetAsync(d_out, 0, (size_t)out_size * sizeof(float), stream);
  hist_kernel<<<1024, 256, 0, stream>>>(dst, cnt, E);
  scan_blocks<<<NB, 256, 0, stream>>>(cnt, binst, tileoff, esum, tsum, N);
  scan_tops<<<1, 256, 0, stream>>>(esum, tsum, Tcnt, NB);
  scan_apply<<<NB, 256, 0, stream>>>(binst, tileoff, cursor, esum, tsum, N);
  if (use16)
    ef16_kernel<<<2048, 256, 0, stream>>>(edge_feats, ef16, (long long)E * 8);
  fill_kernel<<<1024, 256, 0, stream>>>(dst, src, mirror, edge_weights,
                                        cursor, rec, E);
  emit_tiles<<<256, 256, 0, stream>>>(cnt, binst, tileoff, tileA, tileB, N);
  if (use16)
    gather_tiles3_kernel<true><<<4096, 256, 0, stream>>>(
        edge_feats, ef16, rec, tileA, tileB, Tcnt, W_edge, b_edge, h,
        (float*)d_out);
  else
    gather_tiles3_kernel<false><<<4096, 256, 0, stream>>>(
        edge_feats, ef16, rec, tileA, tileB, Tcnt, W_edge, b_edge, h,
        (float*)d_out);
}

// Round 8
// 259.088 us; speedup vs baseline: 1.1566x; 1.1566x over previous
//
#include <hip/hip_runtime.h>
#include <hip/hip_bf16.h>

#define EPSV 1e-5f

typedef __attribute__((ext_vector_type(8))) short bf16x8;
typedef __attribute__((ext_vector_type(4))) float f32x4;

static __device__ __forceinline__ short f2bf(float f) {
  return __builtin_bit_cast(short, __float2bfloat16(f));
}

// ---------------- custom zero (replaces fillBufferAligned path) ----------------
__global__ __launch_bounds__(256) void zero2_kernel(
    int4* __restrict__ p1, long long n1,   // in int4 units
    int4* __restrict__ p2, long long n2)
{
  const long long stride = (long long)gridDim.x * blockDim.x;
  const int4 z = make_int4(0, 0, 0, 0);
  for (long long i = blockIdx.x * (long long)blockDim.x + threadIdx.x;
       i < n1; i += stride) p1[i] = z;
  for (long long i = blockIdx.x * (long long)blockDim.x + threadIdx.x;
       i < n2; i += stride) p2[i] = z;
}

// ---------------- node pipeline: MFMA (unchanged from R6) ----------------
__global__ __launch_bounds__(256) void node_mfma_kernel(
    const float* __restrict__ node_feats, const float* __restrict__ cond,
    const float* __restrict__ W_cond, const float* __restrict__ b_cond,
    const float* __restrict__ W_film, const float* __restrict__ b_film,
    float* __restrict__ h, int N)
{
  __shared__ __align__(16) short cond_s[16][264];
  __shared__ __align__(16) short nf_s[16][136];
  __shared__ __align__(16) float gb_s[16][132];
  __shared__ __align__(16) float h_s[16][68];

  const int t = threadIdx.x;
  const int lane = t & 63;
  const int w = t >> 6;
  const int r16 = lane & 15;
  const int kb = lane >> 4;

  const int colc0 = w * 32 + r16;
  const int colc1 = w * 32 + 16 + r16;
  bf16x8 bc[2][8];
#pragma unroll
  for (int ks = 0; ks < 8; ++ks)
#pragma unroll
    for (int j = 0; j < 8; ++j) {
      const int k = ks * 32 + kb * 8 + j;
      bc[0][ks][j] = f2bf(W_cond[k * 128 + colc0]);
      bc[1][ks][j] = f2bf(W_cond[k * 128 + colc1]);
    }
  const int colf = w * 16 + r16;
  bf16x8 bfm[4];
#pragma unroll
  for (int ks = 0; ks < 4; ++ks)
#pragma unroll
    for (int j = 0; j < 8; ++j)
      bfm[ks][j] = f2bf(W_film[(ks * 32 + kb * 8 + j) * 64 + colf]);
  const float bbc0 = b_cond[colc0] + (w < 2 ? 1.0f : 0.0f);
  const float bbc1 = b_cond[colc1] + (w < 2 ? 1.0f : 0.0f);
  const float bbf = b_film[colf];

  const int ntiles = (N + 15) >> 4;
  for (int tile = blockIdx.x; tile < ntiles; tile += gridDim.x) {
    const int n0 = tile << 4;
    const int rows = min(16, N - n0);
    {
      const float4* c4 = (const float4*)(cond + (size_t)n0 * 256);
#pragma unroll
      for (int it = 0; it < 4; ++it) {
        const int i = t + it * 256;
        const int row = i >> 6, c = i & 63;
        const float4 v = (row < rows) ? c4[i] : make_float4(0.f, 0.f, 0.f, 0.f);
        short* p = &cond_s[row][c * 4];
        p[0] = f2bf(v.x); p[1] = f2bf(v.y); p[2] = f2bf(v.z); p[3] = f2bf(v.w);
      }
      const float4* n4 = (const float4*)(node_feats + (size_t)n0 * 128);
#pragma unroll
      for (int it = 0; it < 2; ++it) {
        const int i = t + it * 256;
        const int row = i >> 5, c = i & 31;
        const float4 v = (row < rows) ? n4[i] : make_float4(0.f, 0.f, 0.f, 0.f);
        short* p = &nf_s[row][c * 4];
        p[0] = f2bf(v.x); p[1] = f2bf(v.y); p[2] = f2bf(v.z); p[3] = f2bf(v.w);
      }
    }
    __syncthreads();

    f32x4 cg0 = {0.f, 0.f, 0.f, 0.f}, cg1 = {0.f, 0.f, 0.f, 0.f};
#pragma unroll
    for (int ks = 0; ks < 8; ++ks) {
      const bf16x8 a = *(const bf16x8*)&cond_s[r16][ks * 32 + kb * 8];
      cg0 = __builtin_amdgcn_mfma_f32_16x16x32_bf16(a, bc[0][ks], cg0, 0, 0, 0);
      cg1 = __builtin_amdgcn_mfma_f32_16x16x32_bf16(a, bc[1][ks], cg1, 0, 0, 0);
    }
    f32x4 ch = {0.f, 0.f, 0.f, 0.f};
#pragma unroll
    for (int ks = 0; ks < 4; ++ks) {
      const bf16x8 a = *(const bf16x8*)&nf_s[r16][ks * 32 + kb * 8];
      ch = __builtin_amdgcn_mfma_f32_16x16x32_bf16(a, bfm[ks], ch, 0, 0, 0);
    }
#pragma unroll
    for (int j = 0; j < 4; ++j) {
      gb_s[kb * 4 + j][colc0] = cg0[j] + bbc0;
      gb_s[kb * 4 + j][colc1] = cg1[j] + bbc1;
      h_s[kb * 4 + j][colf]   = ch[j] + bbf;
    }
    __syncthreads();

#pragma unroll
    for (int rr = 0; rr < 4; ++rr) {
      const int r = w * 4 + rr;
      const float v = h_s[r][lane];
      float s = v, q = v * v;
#pragma unroll
      for (int off = 1; off < 64; off <<= 1) {
        s += __shfl_xor(s, off, 64);
        q += __shfl_xor(q, off, 64);
      }
      const float mu = s * (1.0f / 64.0f);
      const float var = q * (1.0f / 64.0f) - mu * mu;
      const float hn = (v - mu) * rsqrtf(var + EPSV);
      const float gm = gb_s[r][lane];
      const float bt = gb_s[r][64 + lane];
      if (r < rows)
        h[(size_t)(n0 + r) * 64 + lane] = fmaxf(fmaf(gm, hn, bt), 0.0f);
    }
  }
}

// ---------------- counting sort by dst + tile list ----------------
__global__ __launch_bounds__(256) void hist_kernel(
    const int* __restrict__ dst, int* __restrict__ cnt, int E)
{
  const int stride = gridDim.x * blockDim.x;
  for (int e = blockIdx.x * blockDim.x + threadIdx.x; e < E; e += stride)
    atomicAdd(&cnt[dst[e]], 1);
}

__global__ __launch_bounds__(256) void scan_blocks(
    const int* __restrict__ cnt, int* __restrict__ binst, int* __restrict__ tileoff,
    int* __restrict__ esum, int* __restrict__ tsum, int N)
{
  __shared__ int we[4], wt[4];
  const int t = threadIdx.x, lane = t & 63, w = t >> 6;
  const int i = blockIdx.x * 256 + t;
  const int c  = (i < N) ? cnt[i] : 0;
  const int nt = (c + 15) >> 4;
  int pe = c, pt = nt;
#pragma unroll
  for (int off = 1; off < 64; off <<= 1) {
    const int ae = __shfl_up(pe, off, 64);
    const int at = __shfl_up(pt, off, 64);
    if (lane >= off) { pe += ae; pt += at; }
  }
  if (lane == 63) { we[w] = pe; wt[w] = pt; }
  __syncthreads();
  if (t == 0) {
    int re = 0, rt = 0;
#pragma unroll
    for (int k = 0; k < 4; ++k) { const int a = we[k], b = wt[k]; we[k] = re; wt[k] = rt; re += a; rt += b; }
    esum[blockIdx.x] = re;
    tsum[blockIdx.x] = rt;
  }
  __syncthreads();
  if (i < N) {
    binst[i]   = we[w] + pe - c;
    tileoff[i] = wt[w] + pt - nt;
  }
}

__global__ __launch_bounds__(256) void scan_tops(
    int* __restrict__ esum, int* __restrict__ tsum, int* __restrict__ Tcnt, int NB)
{
  __shared__ int we[4], wt[4];
  const int t = threadIdx.x, lane = t & 63, w = t >> 6;
  const int c  = (t < NB) ? esum[t] : 0;
  const int nt = (t < NB) ? tsum[t] : 0;
  int pe = c, pt = nt;
#pragma unroll
  for (int off = 1; off < 64; off <<= 1) {
    const int ae = __shfl_up(pe, off, 64);
    const int at = __shfl_up(pt, off, 64);
    if (lane >= off) { pe += ae; pt += at; }
  }
  if (lane == 63) { we[w] = pe; wt[w] = pt; }
  __syncthreads();
  if (t == 0) {
    int re = 0, rt = 0;
#pragma unroll
    for (int k = 0; k < 4; ++k) { const int a = we[k], b = wt[k]; we[k] = re; wt[k] = rt; re += a; rt += b; }
    Tcnt[0] = rt;
  }
  __syncthreads();
  if (t < NB) {
    esum[t] = we[w] + pe - c;
    tsum[t] = wt[w] + pt - nt;
  }
}

__global__ __launch_bounds__(256) void scan_apply(
    int* __restrict__ binst, int* __restrict__ tileoff, int* __restrict__ cursor,
    const int* __restrict__ esum, const int* __restrict__ tsum, int N)
{
  const int i = blockIdx.x * 256 + threadIdx.x;
  if (i < N) {
    const int b = binst[i] + esum[blockIdx.x];
    binst[i] = b;
    cursor[i] = b;
    tileoff[i] += tsum[blockIdx.x];
  }
}

__global__ __launch_bounds__(256) void emit_tiles(
    const int* __restrict__ cnt, const int* __restrict__ binst,
    const int* __restrict__ tileoff,
    int* __restrict__ tileA, int* __restrict__ tileB, int N)
{
  const int stride = gridDim.x * blockDim.x;
  for (int d = blockIdx.x * blockDim.x + threadIdx.x; d < N; d += stride) {
    const int c = cnt[d];
    const int tb = tileoff[d];
    const int st = binst[d];
    const int nt = (c + 15) >> 4;
    for (int k = 0; k < nt; ++k) {
      tileA[tb + k] = d | (min(16, c - 16 * k) << 20);
      tileB[tb + k] = st + 16 * k;
    }
  }
}

// fill: packed per-slot record {src, mirror, ew_bits, 0}
__global__ __launch_bounds__(256) void fill_kernel(
    const int* __restrict__ dst, const int* __restrict__ src,
    const int* __restrict__ mirror, const float* __restrict__ ew,
    int* __restrict__ cursor, int4* __restrict__ rec, int E)
{
  const int stride = gridDim.x * blockDim.x;
  for (int e = blockIdx.x * blockDim.x + threadIdx.x; e < E; e += stride) {
    const int pos = atomicAdd(&cursor[dst[e]], 1);
    rec[pos] = make_int4(src[e], mirror[e], __float_as_int(ew[e]), 0);
  }
}

// ---------------- fused gather-MFMA-accumulate, depth-1 software pipeline ----
// Iteration i issues tile i+1's {meta, rec, ef-row loads}, then computes tile i
// with operands issued in iteration i-1; the random ef miss overlaps a full
// tile of MFMA + epilogue.
__global__ __launch_bounds__(256) void gather_tiles_kernel(
    const float* __restrict__ ef32,
    const int4* __restrict__ rec,
    const int* __restrict__ tileA, const int* __restrict__ tileB,
    const int* __restrict__ Tcnt,
    const float* __restrict__ W_edge, const float* __restrict__ b_edge,
    const float* __restrict__ h, float* __restrict__ out)
{
  const int lane = threadIdx.x & 63;
  const int r16  = lane & 15;
  const int kb   = lane >> 4;
  const int gw   = (int)((blockIdx.x * blockDim.x + threadIdx.x) >> 6);
  const int nw   = (int)((gridDim.x * blockDim.x) >> 6);
  const int T    = Tcnt[0];

  bf16x8 bfr[4][2];
#pragma unroll
  for (int nb = 0; nb < 4; ++nb)
#pragma unroll
    for (int ks = 0; ks < 2; ++ks)
#pragma unroll
      for (int j = 0; j < 8; ++j) {
        const int k = ks * 32 + kb * 8 + j;
        bfr[nb][ks][j] = f2bf(W_edge[k * 64 + nb * 16 + r16]);
      }
  float bb[4];
#pragma unroll
  for (int nb = 0; nb < 4; ++nb) bb[nb] = b_edge[nb * 16 + r16];

  if (gw >= T) return;

  // prologue: stage tile gw
  int aC = tileA[gw], stC = tileB[gw];
  bool vC = r16 < (aC >> 20);
  int4 rcC = rec[stC + (vC ? r16 : 0)];
  const float* arC = ef32 + (size_t)(vC ? rcC.y : 0) * 64 + kb * 8;
  f32x4 a0 = *(const f32x4*)(arC);
  f32x4 a1 = *(const f32x4*)(arC + 4);
  f32x4 a2 = *(const f32x4*)(arC + 32);
  f32x4 a3 = *(const f32x4*)(arC + 36);

  for (int ti = gw; ti < T; ti += nw) {
    // ---- issue next tile's loads ----
    const int tn = ti + nw;
    int aN = 0, stN = 0;
    if (tn < T) { aN = tileA[tn]; stN = tileB[tn]; }
    const bool vN = r16 < (aN >> 20);
    const int4 rcN = rec[stN + (vN ? r16 : 0)];
    const float* arN = ef32 + (size_t)(vN ? rcN.y : 0) * 64 + kb * 8;
    const f32x4 n0 = *(const f32x4*)(arN);
    const f32x4 n1 = *(const f32x4*)(arN + 4);
    const f32x4 n2 = *(const f32x4*)(arN + 32);
    const f32x4 n3 = *(const f32x4*)(arN + 36);

    // ---- compute current tile ----
    const int d  = aC & 0xFFFFF;
    const float wv = vC ? __int_as_float(rcC.z) : 0.0f;
    const int sv = rcC.x;

    float ewj[4];
    float hv[4][4];
#pragma unroll
    for (int j = 0; j < 4; ++j) {
      const int row = kb * 4 + j;
      const int sj = __shfl(sv, row, 64);
      ewj[j] = __shfl(wv, row, 64);
      const float* hrow = h + (size_t)sj * 64 + r16;
#pragma unroll
      for (int nb = 0; nb < 4; ++nb) hv[j][nb] = hrow[nb * 16];
    }

    bf16x8 af0, af1;
#pragma unroll
    for (int j = 0; j < 4; ++j) {
      af0[j]     = f2bf(a0[j]);
      af0[j + 4] = f2bf(a1[j]);
      af1[j]     = f2bf(a2[j]);
      af1[j + 4] = f2bf(a3[j]);
    }

    f32x4 c[4];
#pragma unroll
    for (int nb = 0; nb < 4; ++nb) c[nb] = (f32x4){0.f, 0.f, 0.f, 0.f};
#pragma unroll
    for (int nb = 0; nb < 4; ++nb) {
      c[nb] = __builtin_amdgcn_mfma_f32_16x16x32_bf16(af0, bfr[nb][0], c[nb], 0, 0, 0);
      c[nb] = __builtin_amdgcn_mfma_f32_16x16x32_bf16(af1, bfr[nb][1], c[nb], 0, 0, 0);
    }

    float racc[4];
#pragma unroll
    for (int nb = 0; nb < 4; ++nb) {
      const float s0 = c[nb][0] + bb[nb];
      const float s1 = c[nb][1] + bb[nb];
      const float s2 = c[nb][2] + bb[nb];
      const float s3 = c[nb][3] + bb[nb];
      float r = (1.0f - 2.0f / (__expf(2.0f * s0) + 1.0f)) * ewj[0] * hv[0][nb];
      r = fmaf((1.0f - 2.0f / (__expf(2.0f * s1) + 1.0f)) * ewj[1], hv[1][nb], r);
      r = fmaf((1.0f - 2.0f / (__expf(2.0f * s2) + 1.0f)) * ewj[2], hv[2][nb], r);
      r = fmaf((1.0f - 2.0f / (__expf(2.0f * s3) + 1.0f)) * ewj[3], hv[3][nb], r);
      r += __shfl_xor(r, 16, 64);
      r += __shfl_xor(r, 32, 64);
      racc[nb] = r;
    }
    float v = racc[0];
    if (kb == 1) v = racc[1];
    if (kb == 2) v = racc[2];
    if (kb == 3) v = racc[3];
    atomicAdd(&out[(size_t)d * 64 + lane], v);

    // ---- rotate pipeline ----
    aC = aN; stC = stN; vC = vN; rcC = rcN;
    a0 = n0; a1 = n1; a2 = n2; a3 = n3;
  }
}

extern "C" void kernel_launch(void* const* d_in, const int* in_sizes, int n_in,
                              void* d_out, int out_size, void* d_ws, size_t ws_size,
                              hipStream_t stream) {
  const float* node_feats   = (const float*)d_in[0];
  const float* edge_feats   = (const float*)d_in[1];
  const float* cond         = (const float*)d_in[2];
  const float* edge_weights = (const float*)d_in[3];
  const int*   src          = (const int*)d_in[4];
  const int*   dst          = (const int*)d_in[5];
  const int*   mirror       = (const int*)d_in[6];
  const float* W_edge       = (const float*)d_in[7];
  const float* b_edge       = (const float*)d_in[8];
  const float* W_cond       = (const float*)d_in[9];
  const float* b_cond       = (const float*)d_in[10];
  const float* W_film       = (const float*)d_in[11];
  const float* b_film       = (const float*)d_in[12];
  const int N = in_sizes[0] / 128;
  const int E = in_sizes[4];
  const int NB = (N + 255) / 256;
  const int Tmax = N + E / 16 + 1;

  char* ws = (char*)d_ws;
  float* h      = (float*)ws;  ws += (size_t)N * 64 * sizeof(float);
  int* cnt      = (int*)ws;    ws += (size_t)((N + 3) & ~3) * sizeof(int);
  int* binst    = (int*)ws;    ws += (size_t)N * sizeof(int);
  int* tileoff  = (int*)ws;    ws += (size_t)N * sizeof(int);
  int* cursor   = (int*)ws;    ws += (size_t)N * sizeof(int);
  int* tileA    = (int*)ws;    ws += (size_t)Tmax * sizeof(int);
  int* tileB    = (int*)ws;    ws += (size_t)Tmax * sizeof(int);
  int* esum     = (int*)ws;    ws += 256 * sizeof(int);
  int* tsum     = (int*)ws;    ws += 256 * sizeof(int);
  int* Tcnt     = (int*)ws;    ws += 320 * sizeof(int);   // pad to 16B boundary
  int4* rec     = (int4*)ws;   ws += (size_t)E * sizeof(int4);

  node_mfma_kernel<<<1024, 256, 0, stream>>>(
      node_feats, cond, W_cond, b_cond, W_film, b_film, h, N);

  // custom zero of cnt (N ints) + d_out (out_size floats); both 16B-aligned
  zero2_kernel<<<512, 256, 0, stream>>>(
      (int4*)cnt, (long long)((N + 3) / 4),
      (int4*)d_out, (long long)(out_size / 4));

  hist_kernel<<<1024, 256, 0, stream>>>(dst, cnt, E);
  scan_blocks<<<NB, 256, 0, stream>>>(cnt, binst, tileoff, esum, tsum, N);
  scan_tops<<<1, 256, 0, stream>>>(esum, tsum, Tcnt, NB);
  scan_apply<<<NB, 256, 0, stream>>>(binst, tileoff, cursor, esum, tsum, N);
  fill_kernel<<<1024, 256, 0, stream>>>(dst, src, mirror, edge_weights,
                                        cursor, rec, E);
  emit_tiles<<<256, 256, 0, stream>>>(cnt, binst, tileoff, tileA, tileB, N);
  gather_tiles_kernel<<<4096, 256, 0, stream>>>(
      edge_feats, rec, tileA, tileB, Tcnt, W_edge, b_edge, h, (float*)d_out);
}